// Round 1
// baseline (909.548 us; speedup 1.0000x reference)
//
#include <hip/hip_runtime.h>

#define B_ 64
#define T_ 512
#define I_ 128
#define H_ 1024
#define O_ 128

typedef unsigned short u16;
typedef unsigned int u32;
typedef __attribute__((ext_vector_type(8))) short short8v;
typedef __attribute__((ext_vector_type(4))) float float4v;

__device__ __forceinline__ u16 f2bf(float f) {
  union { float f; u32 u; } v; v.f = f;
  u32 r = v.u + 0x7FFF + ((v.u >> 16) & 1);
  return (u16)(r >> 16);
}
__device__ __forceinline__ float bf2f(u16 b) {
  union { u32 u; float f; } v; v.u = ((u32)b) << 16;
  return v.f;
}

// ---- prep: xT[t*B+b][i] = bf16(x[b][t][i]) ----
__global__ __launch_bounds__(256) void prep_xT(const float* __restrict__ x, u16* __restrict__ xT) {
  int idx = blockIdx.x * 256 + threadIdx.x;      // < T_*B_*I_ = 4194304
  int i = idx & (I_ - 1);
  int r = idx >> 7;
  int b = r & (B_ - 1);
  int t = r >> 6;
  xT[idx] = f2bf(x[((size_t)b * T_ + t) * I_ + i]);
}

// ---- prep: out[n][k] = bf16(in[k][n]), in is [K][N] row-major ----
__global__ __launch_bounds__(256) void transpose_bf16(const float* __restrict__ in, u16* __restrict__ out,
                                                      int K, int N) {
  int idx = blockIdx.x * 256 + threadIdx.x;
  if (idx >= K * N) return;
  int n = idx / K, k = idx - n * K;
  out[idx] = f2bf(in[(size_t)k * N + n]);
}

// ---- bf16 MFMA GEMM: C[M x 1024] = A[M x K] @ B[K x 1024] (+bias), B given transposed [1024][K].
// 128x128 tile, 4 waves of 64x64, BK=32, single-buffered LDS. Output bf16.
template <int K, bool BIAS>
__global__ __launch_bounds__(256) void gemm_bf16(const u16* __restrict__ A, const u16* __restrict__ Bt,
                                                 u16* __restrict__ C, const float* __restrict__ bias) {
  __shared__ u16 As[128][40];   // +8 pad
  __shared__ u16 Bs[128][40];   // Bs[n][k]
  const int tid = threadIdx.x;
  const int bm = blockIdx.x, bn = blockIdx.y;
  const int lane = tid & 63, w = tid >> 6;
  const int wr = w >> 1, wc = w & 1;
  const int l16 = lane & 15, lq = lane >> 4;

  float4v acc[4][4];
#pragma unroll
  for (int mi = 0; mi < 4; ++mi)
#pragma unroll
    for (int ni = 0; ni < 4; ++ni)
#pragma unroll
      for (int j = 0; j < 4; ++j) acc[mi][ni][j] = 0.f;

  const int sr = tid >> 1;           // staging row 0..127
  const int sc = (tid & 1) << 4;     // 0 or 16
  const u16* Ag = A + ((size_t)(bm * 128 + sr)) * K + sc;
  const u16* Bg = Bt + ((size_t)(bn * 128 + sr)) * K + sc;

  for (int k0 = 0; k0 < K; k0 += 32) {
    uint4 a0 = *(const uint4*)(Ag + k0);
    uint4 a1 = *(const uint4*)(Ag + k0 + 8);
    uint4 b0 = *(const uint4*)(Bg + k0);
    uint4 b1 = *(const uint4*)(Bg + k0 + 8);
    __syncthreads();
    *(uint4*)&As[sr][sc] = a0;
    *(uint4*)&As[sr][sc + 8] = a1;
    *(uint4*)&Bs[sr][sc] = b0;
    *(uint4*)&Bs[sr][sc + 8] = b1;
    __syncthreads();
    short8v a[4], bf[4];
#pragma unroll
    for (int mi = 0; mi < 4; ++mi) a[mi] = *(const short8v*)&As[wr * 64 + mi * 16 + l16][lq * 8];
#pragma unroll
    for (int ni = 0; ni < 4; ++ni) bf[ni] = *(const short8v*)&Bs[wc * 64 + ni * 16 + l16][lq * 8];
#pragma unroll
    for (int mi = 0; mi < 4; ++mi)
#pragma unroll
      for (int ni = 0; ni < 4; ++ni)
        acc[mi][ni] = __builtin_amdgcn_mfma_f32_16x16x32_bf16(a[mi], bf[ni], acc[mi][ni], 0, 0, 0);
  }

#pragma unroll
  for (int mi = 0; mi < 4; ++mi)
#pragma unroll
    for (int ni = 0; ni < 4; ++ni) {
      const int row = bm * 128 + wr * 64 + mi * 16 + lq * 4;
      const int col = bn * 128 + wc * 64 + ni * 16 + l16;
      const float bv = BIAS ? bias[col] : 0.f;
#pragma unroll
      for (int j = 0; j < 4; ++j) C[(size_t)(row + j) * H_ + col] = f2bf(acc[mi][ni][j] + bv);
    }
}

// ---- h1 scan: 2048 independent 32-block scans; u (bf16, [T][B][H]) overwritten with relu(h1) ----
__global__ __launch_bounds__(256) void h1_scan(u16* __restrict__ u, const float* __restrict__ s1,
                                               const float* __restrict__ b1) {
  const int g = blockIdx.x;                 // 0..255
  const int b = g >> 2;
  const int h = ((g & 3) << 8) + threadIdx.x;
  const int lane = threadIdx.x & 31;        // position within 32-block
  const float sc = s1[h] * 0.17677669529663687f;  // s1 / sqrt(32)
  const float bb = b1[h];
  u16* p = u + (size_t)b * H_ + h;
  const size_t stride = (size_t)B_ * H_;
  float x = 0.f;
  u16 uv[8];
#pragma unroll
  for (int d = 0; d < 8; ++d) uv[d] = p[(size_t)d * stride];
  for (int t0 = 0; t0 < T_; t0 += 8) {
#pragma unroll
    for (int d = 0; d < 8; ++d) {
      const int t = t0 + d;
      const float uval = bf2f(uv[d]);
#pragma unroll
      for (int s = 0; s < 5; ++s) {
        const int m = 1 << s;
        float y = __shfl_xor(x, m);
        x = (lane & m) ? (y - x) : (x + y);
      }
      x = sc * x + bb + uval;
      p[(size_t)t * stride] = f2bf(fmaxf(x, 0.f));
      const int tn = t + 8;
      if (tn < T_) uv[d] = p[(size_t)tn * stride];
    }
  }
}

// ---- h2 scan: one wave per batch row; 1024-pt FWHT per step (16 regs/lane), only final h2 kept ----
__global__ __launch_bounds__(64) void h2_scan(const u16* __restrict__ V, float* __restrict__ h2,
                                              const float* __restrict__ s2) {
  const int b = blockIdx.x;
  const int lane = threadIdx.x;
  float x[16], sc2[16];
#pragma unroll
  for (int r = 0; r < 16; ++r) {
    x[r] = 0.f;
    sc2[r] = s2[r * 64 + lane] * 0.03125f;  // s2 / sqrt(1024)
  }
  const u16* p = V + (size_t)b * H_ + lane;
  const size_t stride = (size_t)B_ * H_;
  u16 vs[16];
#pragma unroll
  for (int r = 0; r < 16; ++r) vs[r] = p[r * 64];
  for (int t = 0; t < T_; ++t) {
    const int tn = (t + 1 < T_) ? (t + 1) : t;
    const u16* pn = p + (size_t)tn * stride;
    u16 vn[16];
#pragma unroll
    for (int r = 0; r < 16; ++r) vn[r] = pn[r * 64];
    // in-register butterfly stages (element strides 64,128,256,512)
#pragma unroll
    for (int s = 1; s < 16; s <<= 1) {
#pragma unroll
      for (int r = 0; r < 16; ++r)
        if (!(r & s)) {
          const float a0 = x[r], b0 = x[r | s];
          x[r] = a0 + b0;
          x[r | s] = a0 - b0;
        }
    }
    // cross-lane stages (element strides 1..32)
#pragma unroll
    for (int s = 0; s < 6; ++s) {
      const int m = 1 << s;
      const bool hi = (lane & m) != 0;
#pragma unroll
      for (int r = 0; r < 16; ++r) {
        const float y = __shfl_xor(x[r], m);
        x[r] = hi ? (y - x[r]) : (x[r] + y);
      }
    }
#pragma unroll
    for (int r = 0; r < 16; ++r) x[r] = sc2[r] * x[r] + bf2f(vs[r]);
#pragma unroll
    for (int r = 0; r < 16; ++r) vs[r] = vn[r];
  }
#pragma unroll
  for (int r = 0; r < 16; ++r) h2[(size_t)b * H_ + r * 64 + lane] = x[r];
}

// ---- final: out[b][o] = relu(h2[b]) . W_out[:,o] + b_out[o] ----
__global__ __launch_bounds__(128) void final_out(const float* __restrict__ h2, const float* __restrict__ W_out,
                                                 const float* __restrict__ b_out, float* __restrict__ out) {
  __shared__ float hrow[H_];
  const int b = blockIdx.x, o = threadIdx.x;
  for (int i = o; i < H_; i += 128) hrow[i] = fmaxf(h2[(size_t)b * H_ + i], 0.f);
  __syncthreads();
  float acc = b_out[o];
  for (int h = 0; h < H_; ++h) acc = fmaf(hrow[h], W_out[(size_t)h * O_ + o], acc);
  out[b * O_ + o] = acc;
}

extern "C" void kernel_launch(void* const* d_in, const int* in_sizes, int n_in,
                              void* d_out, int out_size, void* d_ws, size_t ws_size,
                              hipStream_t stream) {
  const float* x     = (const float*)d_in[0];
  const float* W_in  = (const float*)d_in[1];
  const float* s1    = (const float*)d_in[2];
  const float* b1    = (const float*)d_in[3];
  const float* s2    = (const float*)d_in[4];
  const float* b2    = (const float*)d_in[5];
  const float* Wbn   = (const float*)d_in[6];
  const float* W_out = (const float*)d_in[7];
  const float* b_out = (const float*)d_in[8];
  float* out = (float*)d_out;

  // workspace layout (total ~145.3 MB)
  char* ws = (char*)d_ws;
  u16* u    = (u16*)ws;                      // T*B*H bf16 = 64MB  (u, then overwritten by relu(h1))
  u16* V    = (u16*)(ws + 67108864);         // 64MB
  u16* xT   = (u16*)(ws + 134217728);        // 8MB
  u16* WbnT = (u16*)(ws + 142606336);        // 2MB
  u16* WinT = (u16*)(ws + 144703488);        // 256KB
  float* h2 = (float*)(ws + 144965632);      // 256KB

  prep_xT<<<16384, 256, 0, stream>>>(x, xT);
  transpose_bf16<<<4096, 256, 0, stream>>>(Wbn, WbnT, 1024, 1024);
  transpose_bf16<<<512, 256, 0, stream>>>(W_in, WinT, 128, 1024);
  gemm_bf16<128, false><<<dim3(256, 8), 256, 0, stream>>>(xT, WinT, u, nullptr);
  h1_scan<<<256, 256, 0, stream>>>(u, s1, b1);
  gemm_bf16<1024, true><<<dim3(256, 8), 256, 0, stream>>>(u, WbnT, V, b2);
  h2_scan<<<64, 64, 0, stream>>>(V, h2, s2);
  final_out<<<64, 128, 0, stream>>>(h2, W_out, b_out, out);
}

// Round 2
// 529.290 us; speedup vs baseline: 1.7184x; 1.7184x over previous
//
#include <hip/hip_runtime.h>

#define B_ 64
#define T_ 512
#define I_ 128
#define H_ 1024
#define O_ 128

typedef unsigned short u16;
typedef unsigned int u32;
typedef __attribute__((ext_vector_type(8))) short short8v;
typedef __attribute__((ext_vector_type(4))) float float4v;

__device__ __forceinline__ u16 f2bf(float f) {
  union { float f; u32 u; } v; v.f = f;
  u32 r = v.u + 0x7FFF + ((v.u >> 16) & 1);
  return (u16)(r >> 16);
}
__device__ __forceinline__ float bf2f(u16 b) {
  union { u32 u; float f; } v; v.u = ((u32)b) << 16;
  return v.f;
}

// ---- prep: xT[t*B+b][i] = bf16(x[b][t][i]) ----
__global__ __launch_bounds__(256) void prep_xT(const float* __restrict__ x, u16* __restrict__ xT) {
  int idx = blockIdx.x * 256 + threadIdx.x;      // < T_*B_*I_ = 4194304
  int i = idx & (I_ - 1);
  int r = idx >> 7;
  int b = r & (B_ - 1);
  int t = r >> 6;
  xT[idx] = f2bf(x[((size_t)b * T_ + t) * I_ + i]);
}

// ---- prep: out[n][k] = bf16(in[k][n]), in is [K][N] row-major ----
__global__ __launch_bounds__(256) void transpose_bf16(const float* __restrict__ in, u16* __restrict__ out,
                                                      int K, int N) {
  int idx = blockIdx.x * 256 + threadIdx.x;
  if (idx >= K * N) return;
  int n = idx / K, k = idx - n * K;
  out[idx] = f2bf(in[(size_t)k * N + n]);
}

// ---- bf16 MFMA GEMM: C[M x 1024] = A[M x K] @ B[K x 1024] (+bias), B given transposed [1024][K].
template <int K, bool BIAS>
__global__ __launch_bounds__(256) void gemm_bf16(const u16* __restrict__ A, const u16* __restrict__ Bt,
                                                 u16* __restrict__ C, const float* __restrict__ bias) {
  __shared__ u16 As[128][40];   // +8 pad
  __shared__ u16 Bs[128][40];   // Bs[n][k]
  const int tid = threadIdx.x;
  const int bm = blockIdx.x, bn = blockIdx.y;
  const int lane = tid & 63, w = tid >> 6;
  const int wr = w >> 1, wc = w & 1;
  const int l16 = lane & 15, lq = lane >> 4;

  float4v acc[4][4];
#pragma unroll
  for (int mi = 0; mi < 4; ++mi)
#pragma unroll
    for (int ni = 0; ni < 4; ++ni)
#pragma unroll
      for (int j = 0; j < 4; ++j) acc[mi][ni][j] = 0.f;

  const int sr = tid >> 1;           // staging row 0..127
  const int sc = (tid & 1) << 4;     // 0 or 16
  const u16* Ag = A + ((size_t)(bm * 128 + sr)) * K + sc;
  const u16* Bg = Bt + ((size_t)(bn * 128 + sr)) * K + sc;

  for (int k0 = 0; k0 < K; k0 += 32) {
    uint4 a0 = *(const uint4*)(Ag + k0);
    uint4 a1 = *(const uint4*)(Ag + k0 + 8);
    uint4 b0 = *(const uint4*)(Bg + k0);
    uint4 b1 = *(const uint4*)(Bg + k0 + 8);
    __syncthreads();
    *(uint4*)&As[sr][sc] = a0;
    *(uint4*)&As[sr][sc + 8] = a1;
    *(uint4*)&Bs[sr][sc] = b0;
    *(uint4*)&Bs[sr][sc + 8] = b1;
    __syncthreads();
    short8v a[4], bf[4];
#pragma unroll
    for (int mi = 0; mi < 4; ++mi) a[mi] = *(const short8v*)&As[wr * 64 + mi * 16 + l16][lq * 8];
#pragma unroll
    for (int ni = 0; ni < 4; ++ni) bf[ni] = *(const short8v*)&Bs[wc * 64 + ni * 16 + l16][lq * 8];
#pragma unroll
    for (int mi = 0; mi < 4; ++mi)
#pragma unroll
      for (int ni = 0; ni < 4; ++ni)
        acc[mi][ni] = __builtin_amdgcn_mfma_f32_16x16x32_bf16(a[mi], bf[ni], acc[mi][ni], 0, 0, 0);
  }

#pragma unroll
  for (int mi = 0; mi < 4; ++mi)
#pragma unroll
    for (int ni = 0; ni < 4; ++ni) {
      const int row = bm * 128 + wr * 64 + mi * 16 + lq * 4;
      const int col = bn * 128 + wc * 64 + ni * 16 + l16;
      const float bv = BIAS ? bias[col] : 0.f;
#pragma unroll
      for (int j = 0; j < 4; ++j) C[(size_t)(row + j) * H_ + col] = f2bf(acc[mi][ni][j] + bv);
    }
}

// ---- h1 scan: 2048 independent 32-block scans; u (bf16, [T][B][H]) overwritten with relu(h1) ----
__global__ __launch_bounds__(256) void h1_scan(u16* __restrict__ u, const float* __restrict__ s1,
                                               const float* __restrict__ b1) {
  const int g = blockIdx.x;                 // 0..255
  const int b = g >> 2;
  const int h = ((g & 3) << 8) + threadIdx.x;
  const int lane = threadIdx.x & 31;        // position within 32-block
  const float sc = s1[h] * 0.17677669529663687f;  // s1 / sqrt(32)
  const float bb = b1[h];
  u16* p = u + (size_t)b * H_ + h;
  const size_t stride = (size_t)B_ * H_;
  float x = 0.f;
  u16 uv[8];
#pragma unroll
  for (int d = 0; d < 8; ++d) uv[d] = p[(size_t)d * stride];
  for (int t0 = 0; t0 < T_; t0 += 8) {
#pragma unroll
    for (int d = 0; d < 8; ++d) {
      const int t = t0 + d;
      const float uval = bf2f(uv[d]);
#pragma unroll
      for (int s = 0; s < 5; ++s) {
        const int m = 1 << s;
        float y = __shfl_xor(x, m);
        x = (lane & m) ? (y - x) : (x + y);
      }
      x = sc * x + bb + uval;
      p[(size_t)t * stride] = f2bf(fmaxf(x, 0.f));
      const int tn = t + 8;
      if (tn < T_) uv[d] = p[(size_t)tn * stride];
    }
  }
}

// ---- 1024-point FWHT across one wave: 16 regs/lane, element idx = r*64 + lane ----
__device__ __forceinline__ void fwht1024(float* x, int lane) {
#pragma unroll
  for (int s = 1; s < 16; s <<= 1)
#pragma unroll
    for (int r = 0; r < 16; ++r)
      if (!(r & s)) { float a0 = x[r], b0 = x[r | s]; x[r] = a0 + b0; x[r | s] = a0 - b0; }
#pragma unroll
  for (int s = 0; s < 6; ++s) {
    const int m = 1 << s;
    const bool hi = (lane & m) != 0;
#pragma unroll
    for (int r = 0; r < 16; ++r) {
      const float y = __shfl_xor(x[r], m);
      x[r] = hi ? (y - x[r]) : (x[r] + y);
    }
  }
}

// ---- fused: blocks 0..255 compute rows of A^32 (A = diag(s2)Hf); blocks 256..511 do the
//      16x64 within-chunk scans y_c = sum_{t in chunk} A^{...} v_t. 2048 waves total. ----
__global__ __launch_bounds__(256) void fwht_chunk(const u16* __restrict__ V, const float* __restrict__ s2,
                                                  u16* __restrict__ A32, u16* __restrict__ Y) {
  const int W = blockIdx.x * 4 + (threadIdx.x >> 6);
  const int lane = threadIdx.x & 63;
  float x[16], sc[16];
  if (W < 1024) {
    // row W of A^32: Q0 = I, row <- FWHT(s2 .* row)/32, 32 times (right-mult by A)
#pragma unroll
    for (int r = 0; r < 16; ++r) {
      const int idx = r * 64 + lane;
      sc[r] = s2[idx] * 0.03125f;
      x[r] = (idx == W) ? 1.f : 0.f;
    }
    for (int it = 0; it < 32; ++it) {
#pragma unroll
      for (int r = 0; r < 16; ++r) x[r] *= sc[r];
      fwht1024(x, lane);
    }
    u16* dst = A32 + (size_t)W * H_ + lane;
#pragma unroll
    for (int r = 0; r < 16; ++r) dst[r * 64] = f2bf(x[r]);
  } else {
    const int W2 = W - 1024;
    const int c = W2 >> 6, b = W2 & 63;
#pragma unroll
    for (int r = 0; r < 16; ++r) { sc[r] = s2[r * 64 + lane] * 0.03125f; x[r] = 0.f; }
    const u16* p = V + ((size_t)(c * 32) * B_ + b) * H_ + lane;
    const size_t stride = (size_t)B_ * H_;
    u16 v[16];
#pragma unroll
    for (int r = 0; r < 16; ++r) v[r] = p[r * 64];
    for (int j = 0; j < 32; ++j) {
      u16 vn[16];
      if (j + 1 < 32) {
        const u16* pn = p + (size_t)(j + 1) * stride;
#pragma unroll
        for (int r = 0; r < 16; ++r) vn[r] = pn[r * 64];
      }
      fwht1024(x, lane);
#pragma unroll
      for (int r = 0; r < 16; ++r) x[r] = sc[r] * x[r] + bf2f(v[r]);
      if (j + 1 < 32) {
#pragma unroll
        for (int r = 0; r < 16; ++r) v[r] = vn[r];
      }
    }
    u16* dst = Y + ((size_t)c * B_ + b) * H_ + lane;
#pragma unroll
    for (int r = 0; r < 16; ++r) dst[r * 64] = f2bf(x[r]);
  }
}

// ---- combine stage: Znew[64x1024] = Zold @ (A^32)^T + Y_c.  B-frag reads A32 row-major.
//      grid 256: block = (rt 0..3, nt 0..63) -> one 16x16 tile; 4 waves K-split 256 each. ----
template <bool FIRST, bool LAST>
__global__ __launch_bounds__(256) void combine(const u16* __restrict__ Zold, const u16* __restrict__ Yc,
                                               const u16* __restrict__ A32, u16* __restrict__ Znew,
                                               float* __restrict__ h2out) {
  const int rt = blockIdx.x >> 6, nt = blockIdx.x & 63;
  const int tid = threadIdx.x;
  __shared__ float red[4][16][16];
  if (!FIRST) {
    const int w = tid >> 6, lane = tid & 63, l16 = lane & 15, lq = lane >> 4;
    float4v acc = {0.f, 0.f, 0.f, 0.f};
    const u16* Ap = Zold + (size_t)(rt * 16 + l16) * H_ + w * 256 + lq * 8;
    const u16* Bp = A32 + (size_t)(nt * 16 + l16) * H_ + w * 256 + lq * 8;
#pragma unroll
    for (int ks = 0; ks < 8; ++ks) {
      short8v a = *(const short8v*)(Ap + ks * 32);
      short8v bb = *(const short8v*)(Bp + ks * 32);
      acc = __builtin_amdgcn_mfma_f32_16x16x32_bf16(a, bb, acc, 0, 0, 0);
    }
#pragma unroll
    for (int j = 0; j < 4; ++j) red[w][lq * 4 + j][l16] = acc[j];
    __syncthreads();
  } else {
    __syncthreads();
  }
  const int row = tid >> 4, col = tid & 15;
  float s = 0.f;
  if (!FIRST) s = red[0][row][col] + red[1][row][col] + red[2][row][col] + red[3][row][col];
  const int b = rt * 16 + row, n = nt * 16 + col;
  s += bf2f(Yc[(size_t)b * H_ + n]);
  if (LAST) h2out[(size_t)b * H_ + n] = s;
  else Znew[(size_t)b * H_ + n] = f2bf(s);
}

// ---- final: out[b][o] = relu(h2[b]) . W_out[:,o] + b_out[o] ----
__global__ __launch_bounds__(128) void final_out(const float* __restrict__ h2, const float* __restrict__ W_out,
                                                 const float* __restrict__ b_out, float* __restrict__ out) {
  __shared__ float hrow[H_];
  const int b = blockIdx.x, o = threadIdx.x;
  for (int i = o; i < H_; i += 128) hrow[i] = fmaxf(h2[(size_t)b * H_ + i], 0.f);
  __syncthreads();
  float acc = b_out[o];
  for (int h = 0; h < H_; ++h) acc = fmaf(hrow[h], W_out[(size_t)h * O_ + o], acc);
  out[b * O_ + o] = acc;
}

extern "C" void kernel_launch(void* const* d_in, const int* in_sizes, int n_in,
                              void* d_out, int out_size, void* d_ws, size_t ws_size,
                              hipStream_t stream) {
  const float* x     = (const float*)d_in[0];
  const float* W_in  = (const float*)d_in[1];
  const float* s1    = (const float*)d_in[2];
  const float* b1    = (const float*)d_in[3];
  const float* s2    = (const float*)d_in[4];
  const float* b2    = (const float*)d_in[5];
  const float* Wbn   = (const float*)d_in[6];
  const float* W_out = (const float*)d_in[7];
  const float* b_out = (const float*)d_in[8];
  float* out = (float*)d_out;

  // workspace layout (max offset used: 138.25MB, same footprint as round 0)
  char* ws = (char*)d_ws;
  u16* u    = (u16*)ws;                      // 64MB  (u, then relu(h1) in place)
  u16* V    = (u16*)(ws + 67108864);         // 64MB
  u16* xT   = (u16*)(ws + 134217728);        // 8MB, dead after gemm_in
  u16* WbnT = (u16*)(ws + 142606336);        // 2MB
  u16* WinT = (u16*)(ws + 144703488);        // 256KB
  // reuse xT region after gemm_in:
  u16* A32  = (u16*)(ws + 134217728);        // 2MB   (A^32, row-major)
  u16* Y    = (u16*)(ws + 136314880);        // 2MB   ([16][64][1024] bf16)
  u16* Zb0  = (u16*)(ws + 138412032);        // 128KB
  u16* Zb1  = (u16*)(ws + 138543104);        // 128KB
  float* h2 = (float*)(ws + 138674176);      // 256KB

  prep_xT<<<16384, 256, 0, stream>>>(x, xT);
  transpose_bf16<<<4096, 256, 0, stream>>>(Wbn, WbnT, 1024, 1024);
  transpose_bf16<<<512, 256, 0, stream>>>(W_in, WinT, 128, 1024);
  gemm_bf16<128, false><<<dim3(256, 8), 256, 0, stream>>>(xT, WinT, u, nullptr);
  h1_scan<<<256, 256, 0, stream>>>(u, s1, b1);
  gemm_bf16<1024, true><<<dim3(256, 8), 256, 0, stream>>>(u, WbnT, V, b2);
  fwht_chunk<<<512, 256, 0, stream>>>(V, s2, A32, Y);

  u16* Zb[2] = {Zb0, Zb1};
  combine<true, false><<<256, 256, 0, stream>>>(nullptr, Y, A32, Zb[0], nullptr);
  for (int c = 1; c < 15; ++c)
    combine<false, false><<<256, 256, 0, stream>>>(Zb[(c + 1) & 1], Y + (size_t)c * B_ * H_, A32,
                                                   Zb[c & 1], nullptr);
  combine<false, true><<<256, 256, 0, stream>>>(Zb[0], Y + (size_t)15 * B_ * H_, A32, nullptr, h2);

  final_out<<<64, 128, 0, stream>>>(h2, W_out, b_out, out);
}

// Round 4
// 434.335 us; speedup vs baseline: 2.0941x; 1.2186x over previous
//
#include <hip/hip_runtime.h>

#define B_ 64
#define T_ 512
#define I_ 128
#define H_ 1024
#define O_ 128

typedef unsigned short u16;
typedef unsigned int u32;
typedef __attribute__((ext_vector_type(8))) short short8v;
typedef __attribute__((ext_vector_type(4))) float float4v;

__device__ __forceinline__ u16 f2bf(float f) {
  union { float f; u32 u; } v; v.f = f;
  u32 r = v.u + 0x7FFF + ((v.u >> 16) & 1);
  return (u16)(r >> 16);
}
__device__ __forceinline__ float bf2f(u16 b) {
  union { u32 u; float f; } v; v.u = ((u32)b) << 16;
  return v.f;
}

// 32-point FWHT across a 32-lane group (masks 1..16 stay within 32-lane halves of a wave)
__device__ __forceinline__ float fwht32(float x, int lane) {
#pragma unroll
  for (int s = 1; s <= 16; s <<= 1) {
    const float y = __shfl_xor(x, s);
    x = (lane & s) ? (y - x) : (x + y);
  }
  return x;
}

// ---- prep: xT[t*B+b][i] = bf16(x[b][t][i]) ----
__global__ __launch_bounds__(256) void prep_xT(const float* __restrict__ x, u16* __restrict__ xT) {
  int idx = blockIdx.x * 256 + threadIdx.x;      // < T_*B_*I_ = 4194304
  int i = idx & (I_ - 1);
  int r = idx >> 7;
  int b = r & (B_ - 1);
  int t = r >> 6;
  xT[idx] = f2bf(x[((size_t)b * T_ + t) * I_ + i]);
}

// ---- prep: out[n][k] = bf16(in[k][n]), in is [K][N] row-major ----
__global__ __launch_bounds__(256) void transpose_bf16(const float* __restrict__ in, u16* __restrict__ out,
                                                      int K, int N) {
  int idx = blockIdx.x * 256 + threadIdx.x;
  if (idx >= K * N) return;
  int n = idx / K, k = idx - n * K;
  out[idx] = f2bf(in[(size_t)k * N + n]);
}

// ---- bf16 MFMA GEMM: C[M x 1024] = A[M x K] @ B[K x 1024] (+bias), B given transposed [1024][K].
template <int K, bool BIAS>
__global__ __launch_bounds__(256) void gemm_bf16(const u16* __restrict__ A, const u16* __restrict__ Bt,
                                                 u16* __restrict__ C, const float* __restrict__ bias) {
  __shared__ u16 As[128][40];   // +8 pad
  __shared__ u16 Bs[128][40];   // Bs[n][k]
  const int tid = threadIdx.x;
  const int bm = blockIdx.x, bn = blockIdx.y;
  const int lane = tid & 63, w = tid >> 6;
  const int wr = w >> 1, wc = w & 1;
  const int l16 = lane & 15, lq = lane >> 4;

  float4v acc[4][4];
#pragma unroll
  for (int mi = 0; mi < 4; ++mi)
#pragma unroll
    for (int ni = 0; ni < 4; ++ni)
#pragma unroll
      for (int j = 0; j < 4; ++j) acc[mi][ni][j] = 0.f;

  const int sr = tid >> 1;           // staging row 0..127
  const int sc = (tid & 1) << 4;     // 0 or 16
  const u16* Ag = A + ((size_t)(bm * 128 + sr)) * K + sc;
  const u16* Bg = Bt + ((size_t)(bn * 128 + sr)) * K + sc;

  for (int k0 = 0; k0 < K; k0 += 32) {
    uint4 a0 = *(const uint4*)(Ag + k0);
    uint4 a1 = *(const uint4*)(Ag + k0 + 8);
    uint4 b0 = *(const uint4*)(Bg + k0);
    uint4 b1 = *(const uint4*)(Bg + k0 + 8);
    __syncthreads();
    *(uint4*)&As[sr][sc] = a0;
    *(uint4*)&As[sr][sc + 8] = a1;
    *(uint4*)&Bs[sr][sc] = b0;
    *(uint4*)&Bs[sr][sc + 8] = b1;
    __syncthreads();
    short8v a[4], bf[4];
#pragma unroll
    for (int mi = 0; mi < 4; ++mi) a[mi] = *(const short8v*)&As[wr * 64 + mi * 16 + l16][lq * 8];
#pragma unroll
    for (int ni = 0; ni < 4; ++ni) bf[ni] = *(const short8v*)&Bs[wc * 64 + ni * 16 + l16][lq * 8];
#pragma unroll
    for (int mi = 0; mi < 4; ++mi)
#pragma unroll
      for (int ni = 0; ni < 4; ++ni)
        acc[mi][ni] = __builtin_amdgcn_mfma_f32_16x16x32_bf16(a[mi], bf[ni], acc[mi][ni], 0, 0, 0);
  }

#pragma unroll
  for (int mi = 0; mi < 4; ++mi)
#pragma unroll
    for (int ni = 0; ni < 4; ++ni) {
      const int row = bm * 128 + wr * 64 + mi * 16 + lq * 4;
      const int col = bn * 128 + wc * 64 + ni * 16 + l16;
      const float bv = BIAS ? bias[col] : 0.f;
#pragma unroll
      for (int j = 0; j < 4; ++j) C[(size_t)(row + j) * H_ + col] = f2bf(acc[mi][ni][j] + bv);
    }
}

// ---- Pinit: P[hb] = L^32 for L(v) = s1_blk * FWHT32(v)/sqrt(32). One block per hblock.
//      thread = (col j = tid>>5, row r = tid&31); evolve column e_j; store P[hb][r][j]. ----
__global__ __launch_bounds__(1024) void h1_Pinit(const float* __restrict__ s1, float* __restrict__ P) {
  const int hb = blockIdx.x;
  const int tid = threadIdx.x;
  const int j = tid >> 5, r = tid & 31;
  const int lane = tid & 63;
  const float sc = s1[hb * 32 + r] * 0.17677669529663687f;
  float x = (r == j) ? 1.f : 0.f;
  for (int it = 0; it < 32; ++it) x = sc * fwht32(x, lane);
  P[(size_t)hb * 1024 + r * 32 + j] = x;
}

// ---- h1 blocked scan: grid (hpair 0..15, b 0..63), block 1024 = 16 chunks x 64 h.
//      u ([T][B][H] bf16) overwritten in place with relu(h1). ----
__global__ __launch_bounds__(1024, 4) void h1_scan_blocked(u16* __restrict__ u, const float* __restrict__ s1,
                                                           const float* __restrict__ b1,
                                                           const float* __restrict__ P) {
  __shared__ float yLDS[16][64];
  const int hpair = blockIdx.x, b = blockIdx.y;
  const int tid = threadIdx.x;
  const int chunk = tid >> 6;          // 0..15 (= wave id)
  const int hlane = tid & 63;          // h within the 64-wide slice
  const int lane = hlane;              // lane id within wave
  const int h = hpair * 64 + hlane;
  const float sc = s1[h] * 0.17677669529663687f;
  const float bb = b1[h];

  u16* up = u + ((size_t)(chunk * 32) * B_ + b) * H_ + h;
  const size_t stride = (size_t)B_ * H_;

  // ---- Phase A: local scan from zero; keep locals packed bf16 in 16 regs ----
  u32 lpk[16];
  float x = 0.f;
#pragma unroll
  for (int k = 0; k < 32; ++k) {
    const float uval = bf2f(up[(size_t)k * stride]);
    x = sc * fwht32(x, lane) + bb + uval;
    const u16 lb = f2bf(x);
    if (k & 1) lpk[k >> 1] |= ((u32)lb) << 16;
    else       lpk[k >> 1] = (u32)lb;
  }
  yLDS[chunk][hlane] = x;   // chunk-final local state
  __syncthreads();

  // ---- Combine: carry_chunk = sum_{c<chunk} P^{chunk-c} y_c, per-wave serial Horner ----
  const int hb = hlane >> 5, r = hlane & 31;
  const float* Prow = P + ((size_t)(hpair * 2 + hb)) * 1024 + r * 32;
  float pr[32];
#pragma unroll
  for (int jj = 0; jj < 32; ++jj) pr[jj] = Prow[jj];
  float zc = 0.f;
  const int base = hlane & 32;
  for (int c = 0; c < chunk; ++c) {
    const float yv = yLDS[c][hlane];
    float zn = 0.f;
#pragma unroll
    for (int jj = 0; jj < 32; ++jj) zn = fmaf(pr[jj], __shfl(zc, base + jj), zn);
    zc = zn + yv;
  }

  // ---- Phase C: z <- L(z); emit relu(local + z) in place ----
#pragma unroll
  for (int k = 0; k < 32; ++k) {
    zc = sc * fwht32(zc, lane);
    const u16 lb = (k & 1) ? (u16)(lpk[k >> 1] >> 16) : (u16)(lpk[k >> 1] & 0xFFFF);
    const float hv = bf2f(lb) + zc;
    up[(size_t)k * stride] = f2bf(fmaxf(hv, 0.f));
  }
}

// ---- 1024-point FWHT across one wave: 16 regs/lane, element idx = r*64 + lane ----
__device__ __forceinline__ void fwht1024(float* x, int lane) {
#pragma unroll
  for (int s = 1; s < 16; s <<= 1)
#pragma unroll
    for (int r = 0; r < 16; ++r)
      if (!(r & s)) { float a0 = x[r], b0 = x[r | s]; x[r] = a0 + b0; x[r | s] = a0 - b0; }
#pragma unroll
  for (int s = 0; s < 6; ++s) {
    const int m = 1 << s;
    const bool hi = (lane & m) != 0;
#pragma unroll
    for (int r = 0; r < 16; ++r) {
      const float y = __shfl_xor(x[r], m);
      x[r] = hi ? (y - x[r]) : (x[r] + y);
    }
  }
}

// ---- fused: blocks 0..255 compute rows of A^32 (A = diag(s2)Hf); blocks 256..511 do the
//      16x64 within-chunk scans y_c = sum_{t in chunk} A^{...} v_t. 2048 waves total. ----
__global__ __launch_bounds__(256) void fwht_chunk(const u16* __restrict__ V, const float* __restrict__ s2,
                                                  u16* __restrict__ A32, u16* __restrict__ Y) {
  const int W = blockIdx.x * 4 + (threadIdx.x >> 6);
  const int lane = threadIdx.x & 63;
  float x[16], sc[16];
  if (W < 1024) {
#pragma unroll
    for (int r = 0; r < 16; ++r) {
      const int idx = r * 64 + lane;
      sc[r] = s2[idx] * 0.03125f;
      x[r] = (idx == W) ? 1.f : 0.f;
    }
    for (int it = 0; it < 32; ++it) {
#pragma unroll
      for (int r = 0; r < 16; ++r) x[r] *= sc[r];
      fwht1024(x, lane);
    }
    u16* dst = A32 + (size_t)W * H_ + lane;
#pragma unroll
    for (int r = 0; r < 16; ++r) dst[r * 64] = f2bf(x[r]);
  } else {
    const int W2 = W - 1024;
    const int c = W2 >> 6, b = W2 & 63;
#pragma unroll
    for (int r = 0; r < 16; ++r) { sc[r] = s2[r * 64 + lane] * 0.03125f; x[r] = 0.f; }
    const u16* p = V + ((size_t)(c * 32) * B_ + b) * H_ + lane;
    const size_t stride = (size_t)B_ * H_;
    u16 v[16];
#pragma unroll
    for (int r = 0; r < 16; ++r) v[r] = p[r * 64];
    for (int j = 0; j < 32; ++j) {
      u16 vn[16];
      if (j + 1 < 32) {
        const u16* pn = p + (size_t)(j + 1) * stride;
#pragma unroll
        for (int r = 0; r < 16; ++r) vn[r] = pn[r * 64];
      }
      fwht1024(x, lane);
#pragma unroll
      for (int r = 0; r < 16; ++r) x[r] = sc[r] * x[r] + bf2f(v[r]);
      if (j + 1 < 32) {
#pragma unroll
        for (int r = 0; r < 16; ++r) v[r] = vn[r];
      }
    }
    u16* dst = Y + ((size_t)c * B_ + b) * H_ + lane;
#pragma unroll
    for (int r = 0; r < 16; ++r) dst[r * 64] = f2bf(x[r]);
  }
}

// ---- combine stage: Znew[64x1024] = Zold @ (A^32)^T + Y_c. ----
template <bool FIRST, bool LAST>
__global__ __launch_bounds__(256) void combine(const u16* __restrict__ Zold, const u16* __restrict__ Yc,
                                               const u16* __restrict__ A32, u16* __restrict__ Znew,
                                               float* __restrict__ h2out) {
  const int rt = blockIdx.x >> 6, nt = blockIdx.x & 63;
  const int tid = threadIdx.x;
  __shared__ float red[4][16][16];
  if (!FIRST) {
    const int w = tid >> 6, lane = tid & 63, l16 = lane & 15, lq = lane >> 4;
    float4v acc = {0.f, 0.f, 0.f, 0.f};
    const u16* Ap = Zold + (size_t)(rt * 16 + l16) * H_ + w * 256 + lq * 8;
    const u16* Bp = A32 + (size_t)(nt * 16 + l16) * H_ + w * 256 + lq * 8;
#pragma unroll
    for (int ks = 0; ks < 8; ++ks) {
      short8v a = *(const short8v*)(Ap + ks * 32);
      short8v bb = *(const short8v*)(Bp + ks * 32);
      acc = __builtin_amdgcn_mfma_f32_16x16x32_bf16(a, bb, acc, 0, 0, 0);
    }
#pragma unroll
    for (int j = 0; j < 4; ++j) red[w][lq * 4 + j][l16] = acc[j];
    __syncthreads();
  } else {
    __syncthreads();
  }
  const int row = tid >> 4, col = tid & 15;
  float s = 0.f;
  if (!FIRST) s = red[0][row][col] + red[1][row][col] + red[2][row][col] + red[3][row][col];
  const int b = rt * 16 + row, n = nt * 16 + col;
  s += bf2f(Yc[(size_t)b * H_ + n]);
  if (LAST) h2out[(size_t)b * H_ + n] = s;
  else Znew[(size_t)b * H_ + n] = f2bf(s);
}

// ---- final: out[b][o] = relu(h2[b]) . W_out[:,o] + b_out[o] ----
__global__ __launch_bounds__(128) void final_out(const float* __restrict__ h2, const float* __restrict__ W_out,
                                                 const float* __restrict__ b_out, float* __restrict__ out) {
  __shared__ float hrow[H_];
  const int b = blockIdx.x, o = threadIdx.x;
  for (int i = o; i < H_; i += 128) hrow[i] = fmaxf(h2[(size_t)b * H_ + i], 0.f);
  __syncthreads();
  float acc = b_out[o];
  for (int h = 0; h < H_; ++h) acc = fmaf(hrow[h], W_out[(size_t)h * O_ + o], acc);
  out[b * O_ + o] = acc;
}

extern "C" void kernel_launch(void* const* d_in, const int* in_sizes, int n_in,
                              void* d_out, int out_size, void* d_ws, size_t ws_size,
                              hipStream_t stream) {
  const float* x     = (const float*)d_in[0];
  const float* W_in  = (const float*)d_in[1];
  const float* s1    = (const float*)d_in[2];
  const float* b1    = (const float*)d_in[3];
  const float* s2    = (const float*)d_in[4];
  const float* b2    = (const float*)d_in[5];
  const float* Wbn   = (const float*)d_in[6];
  const float* W_out = (const float*)d_in[7];
  const float* b_out = (const float*)d_in[8];
  float* out = (float*)d_out;

  // workspace layout. Live ranges:
  //   u    [0,64MB)           written by gemm_in, consumed through gemm_V
  //   V    [64MB,128MB)       written by gemm_V; FREE before that -> P1 parks here
  //   xT   [128MB,136.4MB)    written by prep_xT, dead after gemm_in
  //   WbnT/WinT               weights
  //   A32/Y/Zb/h2             reuse xT region AFTER gemm_in (xT dead)
  char* ws = (char*)d_ws;
  u16* u    = (u16*)ws;                      // 64MB  (u, then relu(h1) in place)
  u16* V    = (u16*)(ws + 67108864);         // 64MB
  float* P1 = (float*)(ws + 67108864);       // 128KB, aliases V: dead before gemm_V writes V
  u16* xT   = (u16*)(ws + 134217728);        // 8MB, dead after gemm_in
  u16* WbnT = (u16*)(ws + 142606336);        // 2MB
  u16* WinT = (u16*)(ws + 144703488);        // 256KB
  // reuse xT region after gemm_in:
  u16* A32  = (u16*)(ws + 134217728);        // 2MB   (A^32, row-major)
  u16* Y    = (u16*)(ws + 136314880);        // 2MB   ([16][64][1024] bf16)
  u16* Zb0  = (u16*)(ws + 138412032);        // 128KB
  u16* Zb1  = (u16*)(ws + 138543104);        // 128KB
  float* h2 = (float*)(ws + 138674176);      // 256KB

  prep_xT<<<16384, 256, 0, stream>>>(x, xT);
  transpose_bf16<<<4096, 256, 0, stream>>>(Wbn, WbnT, 1024, 1024);
  transpose_bf16<<<512, 256, 0, stream>>>(W_in, WinT, 128, 1024);
  h1_Pinit<<<32, 1024, 0, stream>>>(s1, P1);
  gemm_bf16<128, false><<<dim3(256, 8), 256, 0, stream>>>(xT, WinT, u, nullptr);
  h1_scan_blocked<<<dim3(16, 64), 1024, 0, stream>>>(u, s1, b1, P1);
  gemm_bf16<1024, true><<<dim3(256, 8), 256, 0, stream>>>(u, WbnT, V, b2);
  fwht_chunk<<<512, 256, 0, stream>>>(V, s2, A32, Y);

  u16* Zb[2] = {Zb0, Zb1};
  combine<true, false><<<256, 256, 0, stream>>>(nullptr, Y, A32, Zb[0], nullptr);
  for (int c = 1; c < 15; ++c)
    combine<false, false><<<256, 256, 0, stream>>>(Zb[(c + 1) & 1], Y + (size_t)c * B_ * H_, A32,
                                                   Zb[c & 1], nullptr);
  combine<false, true><<<256, 256, 0, stream>>>(Zb[0], Y + (size_t)15 * B_ * H_, A32, nullptr, h2);

  final_out<<<64, 128, 0, stream>>>(h2, W_out, b_out, out);
}

// Round 5
// 399.138 us; speedup vs baseline: 2.2788x; 1.0882x over previous
//
#include <hip/hip_runtime.h>

#define B_ 64
#define T_ 512
#define I_ 128
#define H_ 1024
#define O_ 128

typedef unsigned short u16;
typedef unsigned int u32;
typedef __attribute__((ext_vector_type(8))) short short8v;
typedef __attribute__((ext_vector_type(4))) float float4v;

typedef __attribute__((address_space(1))) const void gvoid_t;
typedef __attribute__((address_space(3))) void svoid_t;

__device__ __forceinline__ u16 f2bf(float f) {
  union { float f; u32 u; } v; v.f = f;
  u32 r = v.u + 0x7FFF + ((v.u >> 16) & 1);
  return (u16)(r >> 16);
}
__device__ __forceinline__ float bf2f(u16 b) {
  union { u32 u; float f; } v; v.u = ((u32)b) << 16;
  return v.f;
}

// 32-point FWHT across a 32-lane group (masks 1..16 stay within 32-lane halves of a wave)
__device__ __forceinline__ float fwht32(float x, int lane) {
#pragma unroll
  for (int s = 1; s <= 16; s <<= 1) {
    const float y = __shfl_xor(x, s);
    x = (lane & s) ? (y - x) : (x + y);
  }
  return x;
}

// ---- prep: xT[t*B+b][i] = bf16(x[b][t][i]) ----
__global__ __launch_bounds__(256) void prep_xT(const float* __restrict__ x, u16* __restrict__ xT) {
  int idx = blockIdx.x * 256 + threadIdx.x;      // < T_*B_*I_ = 4194304
  int i = idx & (I_ - 1);
  int r = idx >> 7;
  int b = r & (B_ - 1);
  int t = r >> 6;
  xT[idx] = f2bf(x[((size_t)b * T_ + t) * I_ + i]);
}

// ---- prep: out[n][k] = bf16(in[k][n]), in is [K][N] row-major ----
__global__ __launch_bounds__(256) void transpose_bf16(const float* __restrict__ in, u16* __restrict__ out,
                                                      int K, int N) {
  int idx = blockIdx.x * 256 + threadIdx.x;
  if (idx >= K * N) return;
  int n = idx / K, k = idx - n * K;
  out[idx] = f2bf(in[(size_t)k * N + n]);
}

// ---- m97-style bf16 MFMA GEMM: C[M x 1024] = A[M x K] @ B[K x 1024] (+bias).
//      B given transposed [1024][K]. 128x128 tile, 4 waves of 64x64, BK=64,
//      global_load_lds dwordx4 staging into LINEAR LDS with both-sides XOR swizzle:
//      LDS byte for element (row, col): (row*128 + col*2) ^ ((row&7)<<4).
//      Source side: staging lane l (8 lanes/row) fetches col8 = (l&7)^(l>>3).
//      Read side: ds_read_b128 at chunk (ks*4+lq)^(row&7). ----
template <int K, bool BIAS>
__global__ __launch_bounds__(256) void gemm_bf16(const u16* __restrict__ A, const u16* __restrict__ Bt,
                                                 u16* __restrict__ C, const float* __restrict__ bias) {
  __shared__ u16 As[128 * 64];
  __shared__ u16 Bs[128 * 64];
  const int tid = threadIdx.x;
  const int bm = blockIdx.x, bn = blockIdx.y;
  const int lane = tid & 63, w = tid >> 6;
  const int wr = w >> 1, wc = w & 1;
  const int l16 = lane & 15, lq = lane >> 4;

  float4v acc[4][4];
#pragma unroll
  for (int mi = 0; mi < 4; ++mi)
#pragma unroll
    for (int ni = 0; ni < 4; ++ni)
#pragma unroll
      for (int j = 0; j < 4; ++j) acc[mi][ni][j] = 0.f;

  // staging: wave w covers tile rows [w*32, w*32+32), 4 issues of 8 rows each.
  // lane l -> row (w*32 + i*8 + (l>>3)), swizzled col8 = (l&7)^(l>>3)
  const int srow = w * 32 + (lane >> 3);
  const int scol = (((lane & 7) ^ (lane >> 3)) << 3);
  const u16* Ag = A + (size_t)(bm * 128 + srow) * K + scol;
  const u16* Bg = Bt + (size_t)(bn * 128 + srow) * K + scol;

  for (int k0 = 0; k0 < K; k0 += 64) {
    __syncthreads();   // previous tile's ds_reads complete before overwrite
#pragma unroll
    for (int i = 0; i < 4; ++i) {
      __builtin_amdgcn_global_load_lds((gvoid_t*)(Ag + k0 + (size_t)i * 8 * K),
                                       (svoid_t*)&As[(w * 32 + i * 8) * 64], 16, 0, 0);
      __builtin_amdgcn_global_load_lds((gvoid_t*)(Bg + k0 + (size_t)i * 8 * K),
                                       (svoid_t*)&Bs[(w * 32 + i * 8) * 64], 16, 0, 0);
    }
    __syncthreads();   // vmcnt(0) drain -> LDS tile ready
#pragma unroll
    for (int ks = 0; ks < 2; ++ks) {
      short8v a[4], bf[4];
#pragma unroll
      for (int mi = 0; mi < 4; ++mi) {
        const int row = wr * 64 + mi * 16 + l16;
        a[mi] = *(const short8v*)&As[row * 64 + (((ks * 4 + lq) ^ (row & 7)) << 3)];
      }
#pragma unroll
      for (int ni = 0; ni < 4; ++ni) {
        const int row = wc * 64 + ni * 16 + l16;
        bf[ni] = *(const short8v*)&Bs[row * 64 + (((ks * 4 + lq) ^ (row & 7)) << 3)];
      }
#pragma unroll
      for (int mi = 0; mi < 4; ++mi)
#pragma unroll
        for (int ni = 0; ni < 4; ++ni)
          acc[mi][ni] = __builtin_amdgcn_mfma_f32_16x16x32_bf16(a[mi], bf[ni], acc[mi][ni], 0, 0, 0);
    }
  }

#pragma unroll
  for (int mi = 0; mi < 4; ++mi)
#pragma unroll
    for (int ni = 0; ni < 4; ++ni) {
      const int row = bm * 128 + wr * 64 + mi * 16 + lq * 4;
      const int col = bn * 128 + wc * 64 + ni * 16 + l16;
      const float bv = BIAS ? bias[col] : 0.f;
#pragma unroll
      for (int j = 0; j < 4; ++j) C[(size_t)(row + j) * H_ + col] = f2bf(acc[mi][ni][j] + bv);
    }
}

// ---- Pinit: P[hb] = L^32 for L(v) = s1_blk * FWHT32(v)/sqrt(32). One block per hblock.
//      thread = (col j = tid>>5, row r = tid&31); evolve column e_j; store P[hb][r][j]. ----
__global__ __launch_bounds__(1024) void h1_Pinit(const float* __restrict__ s1, float* __restrict__ P) {
  const int hb = blockIdx.x;
  const int tid = threadIdx.x;
  const int j = tid >> 5, r = tid & 31;
  const int lane = tid & 63;
  const float sc = s1[hb * 32 + r] * 0.17677669529663687f;
  float x = (r == j) ? 1.f : 0.f;
  for (int it = 0; it < 32; ++it) x = sc * fwht32(x, lane);
  P[(size_t)hb * 1024 + r * 32 + j] = x;
}

// ---- h1 blocked scan: grid (hpair 0..15, b 0..63), block 1024 = 16 chunks x 64 h.
//      u ([T][B][H] bf16) overwritten in place with relu(h1). ----
__global__ __launch_bounds__(1024, 4) void h1_scan_blocked(u16* __restrict__ u, const float* __restrict__ s1,
                                                           const float* __restrict__ b1,
                                                           const float* __restrict__ P) {
  __shared__ float yLDS[16][64];
  const int hpair = blockIdx.x, b = blockIdx.y;
  const int tid = threadIdx.x;
  const int chunk = tid >> 6;          // 0..15 (= wave id)
  const int hlane = tid & 63;          // h within the 64-wide slice
  const int lane = hlane;              // lane id within wave
  const int h = hpair * 64 + hlane;
  const float sc = s1[h] * 0.17677669529663687f;
  const float bb = b1[h];

  u16* up = u + ((size_t)(chunk * 32) * B_ + b) * H_ + h;
  const size_t stride = (size_t)B_ * H_;

  // ---- Phase A: local scan from zero; keep locals packed bf16 in 16 regs ----
  u32 lpk[16];
  float x = 0.f;
#pragma unroll
  for (int k = 0; k < 32; ++k) {
    const float uval = bf2f(up[(size_t)k * stride]);
    x = sc * fwht32(x, lane) + bb + uval;
    const u16 lb = f2bf(x);
    if (k & 1) lpk[k >> 1] |= ((u32)lb) << 16;
    else       lpk[k >> 1] = (u32)lb;
  }
  yLDS[chunk][hlane] = x;   // chunk-final local state
  __syncthreads();

  // ---- Combine: carry_chunk = sum_{c<chunk} P^{chunk-c} y_c, per-wave serial Horner ----
  const int hb = hlane >> 5, r = hlane & 31;
  const float* Prow = P + ((size_t)(hpair * 2 + hb)) * 1024 + r * 32;
  float pr[32];
#pragma unroll
  for (int jj = 0; jj < 32; ++jj) pr[jj] = Prow[jj];
  float zc = 0.f;
  const int base = hlane & 32;
  for (int c = 0; c < chunk; ++c) {
    const float yv = yLDS[c][hlane];
    float zn = 0.f;
#pragma unroll
    for (int jj = 0; jj < 32; ++jj) zn = fmaf(pr[jj], __shfl(zc, base + jj), zn);
    zc = zn + yv;
  }

  // ---- Phase C: z <- L(z); emit relu(local + z) in place ----
#pragma unroll
  for (int k = 0; k < 32; ++k) {
    zc = sc * fwht32(zc, lane);
    const u16 lb = (k & 1) ? (u16)(lpk[k >> 1] >> 16) : (u16)(lpk[k >> 1] & 0xFFFF);
    const float hv = bf2f(lb) + zc;
    up[(size_t)k * stride] = f2bf(fmaxf(hv, 0.f));
  }
}

// ---- 1024-point FWHT across one wave: 16 regs/lane, element idx = r*64 + lane ----
__device__ __forceinline__ void fwht1024(float* x, int lane) {
#pragma unroll
  for (int s = 1; s < 16; s <<= 1)
#pragma unroll
    for (int r = 0; r < 16; ++r)
      if (!(r & s)) { float a0 = x[r], b0 = x[r | s]; x[r] = a0 + b0; x[r | s] = a0 - b0; }
#pragma unroll
  for (int s = 0; s < 6; ++s) {
    const int m = 1 << s;
    const bool hi = (lane & m) != 0;
#pragma unroll
    for (int r = 0; r < 16; ++r) {
      const float y = __shfl_xor(x[r], m);
      x[r] = hi ? (y - x[r]) : (x[r] + y);
    }
  }
}

// ---- fused: blocks 0..255 compute rows of A^32 (A = diag(s2)Hf); blocks 256..511 do the
//      16x64 within-chunk scans y_c = sum_{t in chunk} A^{...} v_t. 2048 waves total. ----
__global__ __launch_bounds__(256) void fwht_chunk(const u16* __restrict__ V, const float* __restrict__ s2,
                                                  u16* __restrict__ A32, u16* __restrict__ Y) {
  const int W = blockIdx.x * 4 + (threadIdx.x >> 6);
  const int lane = threadIdx.x & 63;
  float x[16], sc[16];
  if (W < 1024) {
#pragma unroll
    for (int r = 0; r < 16; ++r) {
      const int idx = r * 64 + lane;
      sc[r] = s2[idx] * 0.03125f;
      x[r] = (idx == W) ? 1.f : 0.f;
    }
    for (int it = 0; it < 32; ++it) {
#pragma unroll
      for (int r = 0; r < 16; ++r) x[r] *= sc[r];
      fwht1024(x, lane);
    }
    u16* dst = A32 + (size_t)W * H_ + lane;
#pragma unroll
    for (int r = 0; r < 16; ++r) dst[r * 64] = f2bf(x[r]);
  } else {
    const int W2 = W - 1024;
    const int c = W2 >> 6, b = W2 & 63;
#pragma unroll
    for (int r = 0; r < 16; ++r) { sc[r] = s2[r * 64 + lane] * 0.03125f; x[r] = 0.f; }
    const u16* p = V + ((size_t)(c * 32) * B_ + b) * H_ + lane;
    const size_t stride = (size_t)B_ * H_;
    u16 v[16];
#pragma unroll
    for (int r = 0; r < 16; ++r) v[r] = p[r * 64];
    for (int j = 0; j < 32; ++j) {
      u16 vn[16];
      if (j + 1 < 32) {
        const u16* pn = p + (size_t)(j + 1) * stride;
#pragma unroll
        for (int r = 0; r < 16; ++r) vn[r] = pn[r * 64];
      }
      fwht1024(x, lane);
#pragma unroll
      for (int r = 0; r < 16; ++r) x[r] = sc[r] * x[r] + bf2f(v[r]);
      if (j + 1 < 32) {
#pragma unroll
        for (int r = 0; r < 16; ++r) v[r] = vn[r];
      }
    }
    u16* dst = Y + ((size_t)c * B_ + b) * H_ + lane;
#pragma unroll
    for (int r = 0; r < 16; ++r) dst[r * 64] = f2bf(x[r]);
  }
}

// ---- combine stage: Znew[64x1024] = Zold @ (A^32)^T + Y_c. ----
template <bool FIRST, bool LAST>
__global__ __launch_bounds__(256) void combine(const u16* __restrict__ Zold, const u16* __restrict__ Yc,
                                               const u16* __restrict__ A32, u16* __restrict__ Znew,
                                               float* __restrict__ h2out) {
  const int rt = blockIdx.x >> 6, nt = blockIdx.x & 63;
  const int tid = threadIdx.x;
  __shared__ float red[4][16][16];
  if (!FIRST) {
    const int w = tid >> 6, lane = tid & 63, l16 = lane & 15, lq = lane >> 4;
    float4v acc = {0.f, 0.f, 0.f, 0.f};
    const u16* Ap = Zold + (size_t)(rt * 16 + l16) * H_ + w * 256 + lq * 8;
    const u16* Bp = A32 + (size_t)(nt * 16 + l16) * H_ + w * 256 + lq * 8;
#pragma unroll
    for (int ks = 0; ks < 8; ++ks) {
      short8v a = *(const short8v*)(Ap + ks * 32);
      short8v bb = *(const short8v*)(Bp + ks * 32);
      acc = __builtin_amdgcn_mfma_f32_16x16x32_bf16(a, bb, acc, 0, 0, 0);
    }
#pragma unroll
    for (int j = 0; j < 4; ++j) red[w][lq * 4 + j][l16] = acc[j];
    __syncthreads();
  } else {
    __syncthreads();
  }
  const int row = tid >> 4, col = tid & 15;
  float s = 0.f;
  if (!FIRST) s = red[0][row][col] + red[1][row][col] + red[2][row][col] + red[3][row][col];
  const int b = rt * 16 + row, n = nt * 16 + col;
  s += bf2f(Yc[(size_t)b * H_ + n]);
  if (LAST) h2out[(size_t)b * H_ + n] = s;
  else Znew[(size_t)b * H_ + n] = f2bf(s);
}

// ---- final: out[b][o] = relu(h2[b]) . W_out[:,o] + b_out[o] ----
__global__ __launch_bounds__(128) void final_out(const float* __restrict__ h2, const float* __restrict__ W_out,
                                                 const float* __restrict__ b_out, float* __restrict__ out) {
  __shared__ float hrow[H_];
  const int b = blockIdx.x, o = threadIdx.x;
  for (int i = o; i < H_; i += 128) hrow[i] = fmaxf(h2[(size_t)b * H_ + i], 0.f);
  __syncthreads();
  float acc = b_out[o];
  for (int h = 0; h < H_; ++h) acc = fmaf(hrow[h], W_out[(size_t)h * O_ + o], acc);
  out[b * O_ + o] = acc;
}

extern "C" void kernel_launch(void* const* d_in, const int* in_sizes, int n_in,
                              void* d_out, int out_size, void* d_ws, size_t ws_size,
                              hipStream_t stream) {
  const float* x     = (const float*)d_in[0];
  const float* W_in  = (const float*)d_in[1];
  const float* s1    = (const float*)d_in[2];
  const float* b1    = (const float*)d_in[3];
  const float* s2    = (const float*)d_in[4];
  const float* b2    = (const float*)d_in[5];
  const float* Wbn   = (const float*)d_in[6];
  const float* W_out = (const float*)d_in[7];
  const float* b_out = (const float*)d_in[8];
  float* out = (float*)d_out;

  // workspace layout. Live ranges:
  //   u    [0,64MB)           written by gemm_in, consumed through gemm_V
  //   V    [64MB,128MB)       written by gemm_V; FREE before that -> P1 parks here
  //   xT   [128MB,136.4MB)    written by prep_xT, dead after gemm_in
  //   A32/Y/Zb/h2             reuse xT region AFTER gemm_in (xT dead)
  char* ws = (char*)d_ws;
  u16* u    = (u16*)ws;                      // 64MB  (u, then relu(h1) in place)
  u16* V    = (u16*)(ws + 67108864);         // 64MB
  float* P1 = (float*)(ws + 67108864);       // 128KB, aliases V: dead before gemm_V writes V
  u16* xT   = (u16*)(ws + 134217728);        // 8MB, dead after gemm_in
  u16* WbnT = (u16*)(ws + 142606336);        // 2MB
  u16* WinT = (u16*)(ws + 144703488);        // 256KB
  u16* A32  = (u16*)(ws + 134217728);        // 2MB   (A^32, row-major)
  u16* Y    = (u16*)(ws + 136314880);        // 2MB   ([16][64][1024] bf16)
  u16* Zb0  = (u16*)(ws + 138412032);        // 128KB
  u16* Zb1  = (u16*)(ws + 138543104);        // 128KB
  float* h2 = (float*)(ws + 138674176);      // 256KB

  prep_xT<<<16384, 256, 0, stream>>>(x, xT);
  transpose_bf16<<<4096, 256, 0, stream>>>(Wbn, WbnT, 1024, 1024);
  transpose_bf16<<<512, 256, 0, stream>>>(W_in, WinT, 128, 1024);
  h1_Pinit<<<32, 1024, 0, stream>>>(s1, P1);
  gemm_bf16<128, false><<<dim3(256, 8), 256, 0, stream>>>(xT, WinT, u, nullptr);
  h1_scan_blocked<<<dim3(16, 64), 1024, 0, stream>>>(u, s1, b1, P1);
  gemm_bf16<1024, true><<<dim3(256, 8), 256, 0, stream>>>(u, WbnT, V, b2);
  fwht_chunk<<<512, 256, 0, stream>>>(V, s2, A32, Y);

  u16* Zb[2] = {Zb0, Zb1};
  combine<true, false><<<256, 256, 0, stream>>>(nullptr, Y, A32, Zb[0], nullptr);
  for (int c = 1; c < 15; ++c)
    combine<false, false><<<256, 256, 0, stream>>>(Zb[(c + 1) & 1], Y + (size_t)c * B_ * H_, A32,
                                                   Zb[c & 1], nullptr);
  combine<false, true><<<256, 256, 0, stream>>>(Zb[0], Y + (size_t)15 * B_ * H_, A32, nullptr, h2);

  final_out<<<64, 128, 0, stream>>>(h2, W_out, b_out, out);
}

// Round 6
// 353.478 us; speedup vs baseline: 2.5731x; 1.1292x over previous
//
#include <hip/hip_runtime.h>

#define B_ 64
#define T_ 512
#define I_ 128
#define H_ 1024
#define O_ 128

typedef unsigned short u16;
typedef unsigned int u32;
typedef __attribute__((ext_vector_type(8))) short short8v;
typedef __attribute__((ext_vector_type(4))) float float4v;

typedef __attribute__((address_space(1))) const void gvoid_t;
typedef __attribute__((address_space(3))) void svoid_t;

__device__ __forceinline__ u16 f2bf(float f) {
  union { float f; u32 u; } v; v.f = f;
  u32 r = v.u + 0x7FFF + ((v.u >> 16) & 1);
  return (u16)(r >> 16);
}
__device__ __forceinline__ float bf2f(u16 b) {
  union { u32 u; float f; } v; v.u = ((u32)b) << 16;
  return v.f;
}
__device__ __forceinline__ float bits2f(u32 b) {
  union { u32 u; float f; } v; v.u = b;
  return v.f;
}

// 32-point FWHT across a 32-lane group (cross-lane; used only in Pinit)
__device__ __forceinline__ float fwht32(float x, int lane) {
#pragma unroll
  for (int s = 1; s <= 16; s <<= 1) {
    const float y = __shfl_xor(x, s);
    x = (lane & s) ? (y - x) : (x + y);
  }
  return x;
}

// 32-point FWHT fully in registers (pure VALU, zero DS ops)
__device__ __forceinline__ void fwht32_reg(float* x) {
#pragma unroll
  for (int s = 1; s < 32; s <<= 1)
#pragma unroll
    for (int i = 0; i < 32; ++i)
      if (!(i & s)) { const float a = x[i], b = x[i | s]; x[i] = a + b; x[i | s] = a - b; }
}

// ---- prep: xT[t*B+b][i] = bf16(x[b][t][i]) ----
__global__ __launch_bounds__(256) void prep_xT(const float* __restrict__ x, u16* __restrict__ xT) {
  int idx = blockIdx.x * 256 + threadIdx.x;      // < T_*B_*I_ = 4194304
  int i = idx & (I_ - 1);
  int r = idx >> 7;
  int b = r & (B_ - 1);
  int t = r >> 6;
  xT[idx] = f2bf(x[((size_t)b * T_ + t) * I_ + i]);
}

// ---- prep: out[n][k] = bf16(in[k][n]), in is [K][N] row-major ----
__global__ __launch_bounds__(256) void transpose_bf16(const float* __restrict__ in, u16* __restrict__ out,
                                                      int K, int N) {
  int idx = blockIdx.x * 256 + threadIdx.x;
  if (idx >= K * N) return;
  int n = idx / K, k = idx - n * K;
  out[idx] = f2bf(in[(size_t)k * N + n]);
}

// ---- m97-style bf16 MFMA GEMM (as R5): global_load_lds + both-sides XOR swizzle, BK=64 ----
template <int K, bool BIAS>
__global__ __launch_bounds__(256) void gemm_bf16(const u16* __restrict__ A, const u16* __restrict__ Bt,
                                                 u16* __restrict__ C, const float* __restrict__ bias) {
  __shared__ u16 As[128 * 64];
  __shared__ u16 Bs[128 * 64];
  const int tid = threadIdx.x;
  const int bm = blockIdx.x, bn = blockIdx.y;
  const int lane = tid & 63, w = tid >> 6;
  const int wr = w >> 1, wc = w & 1;
  const int l16 = lane & 15, lq = lane >> 4;

  float4v acc[4][4];
#pragma unroll
  for (int mi = 0; mi < 4; ++mi)
#pragma unroll
    for (int ni = 0; ni < 4; ++ni)
#pragma unroll
      for (int j = 0; j < 4; ++j) acc[mi][ni][j] = 0.f;

  const int srow = w * 32 + (lane >> 3);
  const int scol = (((lane & 7) ^ (lane >> 3)) << 3);
  const u16* Ag = A + (size_t)(bm * 128 + srow) * K + scol;
  const u16* Bg = Bt + (size_t)(bn * 128 + srow) * K + scol;

  for (int k0 = 0; k0 < K; k0 += 64) {
    __syncthreads();
#pragma unroll
    for (int i = 0; i < 4; ++i) {
      __builtin_amdgcn_global_load_lds((gvoid_t*)(Ag + k0 + (size_t)i * 8 * K),
                                       (svoid_t*)&As[(w * 32 + i * 8) * 64], 16, 0, 0);
      __builtin_amdgcn_global_load_lds((gvoid_t*)(Bg + k0 + (size_t)i * 8 * K),
                                       (svoid_t*)&Bs[(w * 32 + i * 8) * 64], 16, 0, 0);
    }
    __syncthreads();
#pragma unroll
    for (int ks = 0; ks < 2; ++ks) {
      short8v a[4], bf[4];
#pragma unroll
      for (int mi = 0; mi < 4; ++mi) {
        const int row = wr * 64 + mi * 16 + l16;
        a[mi] = *(const short8v*)&As[row * 64 + (((ks * 4 + lq) ^ (row & 7)) << 3)];
      }
#pragma unroll
      for (int ni = 0; ni < 4; ++ni) {
        const int row = wc * 64 + ni * 16 + l16;
        bf[ni] = *(const short8v*)&Bs[row * 64 + (((ks * 4 + lq) ^ (row & 7)) << 3)];
      }
#pragma unroll
      for (int mi = 0; mi < 4; ++mi)
#pragma unroll
        for (int ni = 0; ni < 4; ++ni)
          acc[mi][ni] = __builtin_amdgcn_mfma_f32_16x16x32_bf16(a[mi], bf[ni], acc[mi][ni], 0, 0, 0);
    }
  }

#pragma unroll
  for (int mi = 0; mi < 4; ++mi)
#pragma unroll
    for (int ni = 0; ni < 4; ++ni) {
      const int row = bm * 128 + wr * 64 + mi * 16 + lq * 4;
      const int col = bn * 128 + wc * 64 + ni * 16 + l16;
      const float bv = BIAS ? bias[col] : 0.f;
#pragma unroll
      for (int j = 0; j < 4; ++j) C[(size_t)(row + j) * H_ + col] = f2bf(acc[mi][ni][j] + bv);
    }
}

// ---- Pinit: P[hb] = L^32 for L(v) = s1_blk * FWHT32(v)/sqrt(32). ----
__global__ __launch_bounds__(1024) void h1_Pinit(const float* __restrict__ s1, float* __restrict__ P) {
  const int hb = blockIdx.x;
  const int tid = threadIdx.x;
  const int j = tid >> 5, r = tid & 31;
  const int lane = tid & 63;
  const float sc = s1[hb * 32 + r] * 0.17677669529663687f;
  float x = (r == j) ? 1.f : 0.f;
  for (int it = 0; it < 32; ++it) x = sc * fwht32(x, lane);
  P[(size_t)hb * 1024 + r * 32 + j] = x;
}

// ---- h1 pass A: per-thread 32-elem block state, in-register FWHT, no DS ops.
//      u already contains (b1 + u). Writes chunk-final local states y to Ybuf. ----
__global__ __launch_bounds__(64) void h1_local(const u16* __restrict__ u, const float* __restrict__ s1,
                                               float* __restrict__ Ybuf) {
  const int g = blockIdx.x * 64 + threadIdx.x;   // 32768 threads: (chunk, b, hb)
  const int hb = g & 31, b = (g >> 5) & 63, chunk = g >> 11;
  float x[32], sc[32];
#pragma unroll
  for (int i = 0; i < 32; i += 4) {
    const float4 s4 = *(const float4*)&s1[hb * 32 + i];
    sc[i] = s4.x * 0.17677669529663687f;
    sc[i + 1] = s4.y * 0.17677669529663687f;
    sc[i + 2] = s4.z * 0.17677669529663687f;
    sc[i + 3] = s4.w * 0.17677669529663687f;
  }
#pragma unroll
  for (int i = 0; i < 32; ++i) x[i] = 0.f;
  const u16* up = u + ((size_t)(chunk * 32) * B_ + b) * H_ + hb * 32;
#pragma unroll 2
  for (int k = 0; k < 32; ++k) {
    u32 wv[16];
#pragma unroll
    for (int j = 0; j < 4; ++j) {
      const uint4 t4 = *(const uint4*)(up + (size_t)k * (B_ * H_) + j * 8);
      wv[4 * j] = t4.x; wv[4 * j + 1] = t4.y; wv[4 * j + 2] = t4.z; wv[4 * j + 3] = t4.w;
    }
    fwht32_reg(x);
#pragma unroll
    for (int i2 = 0; i2 < 16; ++i2) {
      x[2 * i2]     = fmaf(sc[2 * i2],     x[2 * i2],     bits2f(wv[i2] << 16));
      x[2 * i2 + 1] = fmaf(sc[2 * i2 + 1], x[2 * i2 + 1], bits2f(wv[i2] & 0xFFFF0000u));
    }
  }
  float* yp = Ybuf + (size_t)g * 32;
#pragma unroll
  for (int i = 0; i < 32; i += 4) {
    float4 o; o.x = x[i]; o.y = x[i + 1]; o.z = x[i + 2]; o.w = x[i + 3];
    *(float4*)(yp + i) = o;
  }
}

// ---- h1 carry: Z_0 = 0; Z_{c+1} = P·Z_c + y_c. Grid (hpair, b), 1 wave. ----
__global__ __launch_bounds__(64) void h1_carry(const float* __restrict__ P, const float* __restrict__ Ybuf,
                                               float* __restrict__ Zbuf) {
  const int hpair = blockIdx.x, b = blockIdx.y;
  const int lane = threadIdx.x;
  const int r = lane & 31, hb = hpair * 2 + (lane >> 5);
  const float* Prow = P + (size_t)hb * 1024 + r * 32;
  float pr[32];
#pragma unroll
  for (int j = 0; j < 32; ++j) pr[j] = Prow[j];
  float z = 0.f;
  const int base = lane & 32;
  for (int c = 0; c < 16; ++c) {
    Zbuf[(((size_t)c * 64 + b) * 32 + hb) * 32 + r] = z;
    if (c < 15) {
      const float yv = Ybuf[(((size_t)c * 64 + b) * 32 + hb) * 32 + r];
      float zn = 0.f;
#pragma unroll
      for (int j = 0; j < 32; ++j) zn = fmaf(pr[j], __shfl(z, base + j), zn);
      z = zn + yv;
    }
  }
}

// ---- h1 pass C: re-run scan seeded with Z_c; write relu(h1) bf16 in place. ----
__global__ __launch_bounds__(64) void h1_apply(u16* __restrict__ u, const float* __restrict__ s1,
                                               const float* __restrict__ Zbuf) {
  const int g = blockIdx.x * 64 + threadIdx.x;
  const int hb = g & 31, b = (g >> 5) & 63, chunk = g >> 11;
  float x[32], sc[32];
#pragma unroll
  for (int i = 0; i < 32; i += 4) {
    const float4 s4 = *(const float4*)&s1[hb * 32 + i];
    sc[i] = s4.x * 0.17677669529663687f;
    sc[i + 1] = s4.y * 0.17677669529663687f;
    sc[i + 2] = s4.z * 0.17677669529663687f;
    sc[i + 3] = s4.w * 0.17677669529663687f;
  }
  const float* zp = Zbuf + (size_t)g * 32;
#pragma unroll
  for (int i = 0; i < 32; i += 4) {
    const float4 z4 = *(const float4*)(zp + i);
    x[i] = z4.x; x[i + 1] = z4.y; x[i + 2] = z4.z; x[i + 3] = z4.w;
  }
  u16* up = u + ((size_t)(chunk * 32) * B_ + b) * H_ + hb * 32;
#pragma unroll 2
  for (int k = 0; k < 32; ++k) {
    u32 wv[16];
#pragma unroll
    for (int j = 0; j < 4; ++j) {
      const uint4 t4 = *(const uint4*)(up + (size_t)k * (B_ * H_) + j * 8);
      wv[4 * j] = t4.x; wv[4 * j + 1] = t4.y; wv[4 * j + 2] = t4.z; wv[4 * j + 3] = t4.w;
    }
    fwht32_reg(x);
#pragma unroll
    for (int i2 = 0; i2 < 16; ++i2) {
      x[2 * i2]     = fmaf(sc[2 * i2],     x[2 * i2],     bits2f(wv[i2] << 16));
      x[2 * i2 + 1] = fmaf(sc[2 * i2 + 1], x[2 * i2 + 1], bits2f(wv[i2] & 0xFFFF0000u));
    }
    u32 ov[16];
#pragma unroll
    for (int i2 = 0; i2 < 16; ++i2) {
      const u32 lo = f2bf(fmaxf(x[2 * i2], 0.f));
      const u32 hi = f2bf(fmaxf(x[2 * i2 + 1], 0.f));
      ov[i2] = lo | (hi << 16);
    }
#pragma unroll
    for (int j = 0; j < 4; ++j) {
      uint4 t4; t4.x = ov[4 * j]; t4.y = ov[4 * j + 1]; t4.z = ov[4 * j + 2]; t4.w = ov[4 * j + 3];
      *(uint4*)(up + (size_t)k * (B_ * H_) + j * 8) = t4;
    }
  }
}

// ---- 1024-point FWHT across one wave: 16 regs/lane, element idx = r*64 + lane ----
__device__ __forceinline__ void fwht1024(float* x, int lane) {
#pragma unroll
  for (int s = 1; s < 16; s <<= 1)
#pragma unroll
    for (int r = 0; r < 16; ++r)
      if (!(r & s)) { float a0 = x[r], b0 = x[r | s]; x[r] = a0 + b0; x[r | s] = a0 - b0; }
#pragma unroll
  for (int s = 0; s < 6; ++s) {
    const int m = 1 << s;
    const bool hi = (lane & m) != 0;
#pragma unroll
    for (int r = 0; r < 16; ++r) {
      const float y = __shfl_xor(x[r], m);
      x[r] = hi ? (y - x[r]) : (x[r] + y);
    }
  }
}

// ---- fused: blocks 0..255 compute rows of A^32 (A = diag(s2)Hf); blocks 256..511 do the
//      16x64 within-chunk scans y_c = sum_{t in chunk} A^{...} v_t. ----
__global__ __launch_bounds__(256) void fwht_chunk(const u16* __restrict__ V, const float* __restrict__ s2,
                                                  u16* __restrict__ A32, u16* __restrict__ Y) {
  const int W = blockIdx.x * 4 + (threadIdx.x >> 6);
  const int lane = threadIdx.x & 63;
  float x[16], sc[16];
  if (W < 1024) {
#pragma unroll
    for (int r = 0; r < 16; ++r) {
      const int idx = r * 64 + lane;
      sc[r] = s2[idx] * 0.03125f;
      x[r] = (idx == W) ? 1.f : 0.f;
    }
    for (int it = 0; it < 32; ++it) {
#pragma unroll
      for (int r = 0; r < 16; ++r) x[r] *= sc[r];
      fwht1024(x, lane);
    }
    u16* dst = A32 + (size_t)W * H_ + lane;
#pragma unroll
    for (int r = 0; r < 16; ++r) dst[r * 64] = f2bf(x[r]);
  } else {
    const int W2 = W - 1024;
    const int c = W2 >> 6, b = W2 & 63;
#pragma unroll
    for (int r = 0; r < 16; ++r) { sc[r] = s2[r * 64 + lane] * 0.03125f; x[r] = 0.f; }
    const u16* p = V + ((size_t)(c * 32) * B_ + b) * H_ + lane;
    const size_t stride = (size_t)B_ * H_;
    u16 v[16];
#pragma unroll
    for (int r = 0; r < 16; ++r) v[r] = p[r * 64];
    for (int j = 0; j < 32; ++j) {
      u16 vn[16];
      if (j + 1 < 32) {
        const u16* pn = p + (size_t)(j + 1) * stride;
#pragma unroll
        for (int r = 0; r < 16; ++r) vn[r] = pn[r * 64];
      }
      fwht1024(x, lane);
#pragma unroll
      for (int r = 0; r < 16; ++r) x[r] = sc[r] * x[r] + bf2f(v[r]);
      if (j + 1 < 32) {
#pragma unroll
        for (int r = 0; r < 16; ++r) v[r] = vn[r];
      }
    }
    u16* dst = Y + ((size_t)c * B_ + b) * H_ + lane;
#pragma unroll
    for (int r = 0; r < 16; ++r) dst[r * 64] = f2bf(x[r]);
  }
}

// ---- combine stage: Znew[64x1024] = Zold @ (A^32)^T + Y_c. ----
template <bool FIRST, bool LAST>
__global__ __launch_bounds__(256) void combine(const u16* __restrict__ Zold, const u16* __restrict__ Yc,
                                               const u16* __restrict__ A32, u16* __restrict__ Znew,
                                               float* __restrict__ h2out) {
  const int rt = blockIdx.x >> 6, nt = blockIdx.x & 63;
  const int tid = threadIdx.x;
  __shared__ float red[4][16][16];
  if (!FIRST) {
    const int w = tid >> 6, lane = tid & 63, l16 = lane & 15, lq = lane >> 4;
    float4v acc = {0.f, 0.f, 0.f, 0.f};
    const u16* Ap = Zold + (size_t)(rt * 16 + l16) * H_ + w * 256 + lq * 8;
    const u16* Bp = A32 + (size_t)(nt * 16 + l16) * H_ + w * 256 + lq * 8;
#pragma unroll
    for (int ks = 0; ks < 8; ++ks) {
      short8v a = *(const short8v*)(Ap + ks * 32);
      short8v bb = *(const short8v*)(Bp + ks * 32);
      acc = __builtin_amdgcn_mfma_f32_16x16x32_bf16(a, bb, acc, 0, 0, 0);
    }
#pragma unroll
    for (int j = 0; j < 4; ++j) red[w][lq * 4 + j][l16] = acc[j];
    __syncthreads();
  } else {
    __syncthreads();
  }
  const int row = tid >> 4, col = tid & 15;
  float s = 0.f;
  if (!FIRST) s = red[0][row][col] + red[1][row][col] + red[2][row][col] + red[3][row][col];
  const int b = rt * 16 + row, n = nt * 16 + col;
  s += bf2f(Yc[(size_t)b * H_ + n]);
  if (LAST) h2out[(size_t)b * H_ + n] = s;
  else Znew[(size_t)b * H_ + n] = f2bf(s);
}

// ---- final: out[b][o] = relu(h2[b]) . W_out[:,o] + b_out[o] ----
__global__ __launch_bounds__(128) void final_out(const float* __restrict__ h2, const float* __restrict__ W_out,
                                                 const float* __restrict__ b_out, float* __restrict__ out) {
  __shared__ float hrow[H_];
  const int b = blockIdx.x, o = threadIdx.x;
  for (int i = o; i < H_; i += 128) hrow[i] = fmaxf(h2[(size_t)b * H_ + i], 0.f);
  __syncthreads();
  float acc = b_out[o];
  for (int h = 0; h < H_; ++h) acc = fmaf(hrow[h], W_out[(size_t)h * O_ + o], acc);
  out[b * O_ + o] = acc;
}

extern "C" void kernel_launch(void* const* d_in, const int* in_sizes, int n_in,
                              void* d_out, int out_size, void* d_ws, size_t ws_size,
                              hipStream_t stream) {
  const float* x     = (const float*)d_in[0];
  const float* W_in  = (const float*)d_in[1];
  const float* s1    = (const float*)d_in[2];
  const float* b1    = (const float*)d_in[3];
  const float* s2    = (const float*)d_in[4];
  const float* b2    = (const float*)d_in[5];
  const float* Wbn   = (const float*)d_in[6];
  const float* W_out = (const float*)d_in[7];
  const float* b_out = (const float*)d_in[8];
  float* out = (float*)d_out;

  // workspace live ranges:
  //   u    [0,64MB)        gemm_in -> ... -> gemm_V
  //   V    [64MB,128MB)    gemm_V -> fwht_chunk; P1 parks there earlier (dead by gemm_V)
  //   xT   [128MB,136.4MB) prep_xT -> gemm_in; then reused:
  //     Ybuf [128MB,+4MB)  h1_local -> h1_carry      (dead before fwht_chunk writes A32/Y)
  //     Zbuf [132MB,+4MB)  h1_carry -> h1_apply      (dead before combine writes Zb)
  //     A32/Y/Zb/h2 as before (after h1 complete)
  char* ws = (char*)d_ws;
  u16* u      = (u16*)ws;                    // 64MB
  u16* V      = (u16*)(ws + 67108864);       // 64MB
  float* P1   = (float*)(ws + 67108864);     // 128KB, aliases V (dead before gemm_V)
  u16* xT     = (u16*)(ws + 134217728);      // 8MB, dead after gemm_in
  float* Ybuf = (float*)(ws + 134217728);    // 4MB  (aliases xT, used after gemm_in)
  float* Zbuf = (float*)(ws + 138412032);    // 4MB
  u16* WbnT   = (u16*)(ws + 142606336);      // 2MB
  u16* WinT   = (u16*)(ws + 144703488);      // 256KB
  u16* A32    = (u16*)(ws + 134217728);      // 2MB  (after h1 done)
  u16* Y      = (u16*)(ws + 136314880);      // 2MB
  u16* Zb0    = (u16*)(ws + 138412032);      // 128KB (after h1 done)
  u16* Zb1    = (u16*)(ws + 138543104);      // 128KB
  float* h2   = (float*)(ws + 138674176);    // 256KB

  prep_xT<<<16384, 256, 0, stream>>>(x, xT);
  transpose_bf16<<<4096, 256, 0, stream>>>(Wbn, WbnT, 1024, 1024);
  transpose_bf16<<<512, 256, 0, stream>>>(W_in, WinT, 128, 1024);
  h1_Pinit<<<32, 1024, 0, stream>>>(s1, P1);
  gemm_bf16<128, true><<<dim3(256, 8), 256, 0, stream>>>(xT, WinT, u, b1);  // u = x@W_in + b1
  h1_local<<<512, 64, 0, stream>>>(u, s1, Ybuf);
  h1_carry<<<dim3(16, 64), 64, 0, stream>>>(P1, Ybuf, Zbuf);
  h1_apply<<<512, 64, 0, stream>>>(u, s1, Zbuf);
  gemm_bf16<1024, true><<<dim3(256, 8), 256, 0, stream>>>(u, WbnT, V, b2);
  fwht_chunk<<<512, 256, 0, stream>>>(V, s2, A32, Y);

  u16* Zb[2] = {Zb0, Zb1};
  combine<true, false><<<256, 256, 0, stream>>>(nullptr, Y, A32, Zb[0], nullptr);
  for (int c = 1; c < 15; ++c)
    combine<false, false><<<256, 256, 0, stream>>>(Zb[(c + 1) & 1], Y + (size_t)c * B_ * H_, A32,
                                                   Zb[c & 1], nullptr);
  combine<false, true><<<256, 256, 0, stream>>>(Zb[0], Y + (size_t)15 * B_ * H_, A32, nullptr, h2);

  final_out<<<64, 128, 0, stream>>>(h2, W_out, b_out, out);
}